// Round 1
// baseline (215.186 us; speedup 1.0000x reference)
//
#include <hip/hip_runtime.h>
#include <stdint.h>

typedef unsigned short u16;
typedef __attribute__((ext_vector_type(8))) short short8;
typedef __attribute__((ext_vector_type(4))) float f32x4;
typedef __attribute__((ext_vector_type(4))) unsigned short u16x4;

#define DEVI __device__ __forceinline__

DEVI u16 f2bf(float f) {
  uint32_t u = __builtin_bit_cast(uint32_t, f);
  u += 0x7fffu + ((u >> 16) & 1u);
  return (u16)(u >> 16);
}

DEVI void gload_lds16(const void* g, void* l) {
  __builtin_amdgcn_global_load_lds(
      (const __attribute__((address_space(1))) void*)g,
      (__attribute__((address_space(3))) void*)(uint32_t)(uintptr_t)l,
      16, 0, 0);
}

// ---------------- convert / concat fp32 -> bf16 ----------------
__global__ void cvt_cat_bf16(const float* __restrict__ a, const float* __restrict__ b,
                             u16* __restrict__ dst, long total) {
  // dst rows of 2048: cols [0,1024) from a, [1024,2048) from b
  for (long i = ((long)blockIdx.x * 256 + threadIdx.x) * 4; i < total;
       i += (long)gridDim.x * 1024) {
    const long row = i >> 11;
    const long c = i & 2047;
    const float* src = (c < 1024) ? (a + row * 1024 + c) : (b + row * 1024 + (c - 1024));
    const float4 v = *(const float4*)src;
    u16x4 o = {f2bf(v.x), f2bf(v.y), f2bf(v.z), f2bf(v.w)};
    *(u16x4*)(dst + i) = o;
  }
}

__global__ void cvt_bf16(const float* __restrict__ a, u16* __restrict__ dst, long total) {
  for (long i = ((long)blockIdx.x * 256 + threadIdx.x) * 4; i < total;
       i += (long)gridDim.x * 1024) {
    const float4 v = *(const float4*)(a + i);
    u16x4 o = {f2bf(v.x), f2bf(v.y), f2bf(v.z), f2bf(v.w)};
    *(u16x4*)(dst + i) = o;
  }
}

// ---------------- bf16 GEMM, C = A * B^T + bias (m97 structure) ----------------
// A [M,K] bf16 row-major; B [N,K] bf16 row-major (i.e. B^T layout); C [M,N] fp32.
__global__ __launch_bounds__(256, 2)
void gemm_bt(const u16* __restrict__ A, const u16* __restrict__ B,
             float* __restrict__ C, const float* __restrict__ bias1,
             const float* __restrict__ bias2, int M, int N, int K) {
  __shared__ u16 As[128 * 32];
  __shared__ u16 Bs[128 * 32];
  const int t = threadIdx.x;
  const int w = t >> 6, l = t & 63;
  const int l15 = l & 15, lg = l >> 4;
  const int bm = blockIdx.x, bn = blockIdx.y;
  const int wr = (w >> 1) * 64, wc = (w & 1) * 64;
  f32x4 acc[4][4] = {};
  const int c0 = w * 64 + l;

  for (int kt = 0; kt < (K >> 5); ++kt) {
#pragma unroll
    for (int i = 0; i < 2; ++i) {
      const int c = i * 256 + c0;
      const int row = c >> 2, seg = c & 3;
      gload_lds16(A + (long)(bm * 128 + row) * K + kt * 32 + seg * 8,
                  (char*)As + w * 1024 + i * 4096);
      gload_lds16(B + (long)(bn * 128 + row) * K + kt * 32 + seg * 8,
                  (char*)Bs + w * 1024 + i * 4096);
    }
    __syncthreads();
    short8 af[4], bfr[4];
#pragma unroll
    for (int m = 0; m < 4; ++m)
      af[m] = *(const short8*)&As[(wr + m * 16 + l15) * 32 + lg * 8];
#pragma unroll
    for (int n = 0; n < 4; ++n)
      bfr[n] = *(const short8*)&Bs[(wc + n * 16 + l15) * 32 + lg * 8];
#pragma unroll
    for (int m = 0; m < 4; ++m)
#pragma unroll
      for (int n = 0; n < 4; ++n)
        acc[m][n] = __builtin_amdgcn_mfma_f32_16x16x32_bf16(af[m], bfr[n], acc[m][n], 0, 0, 0);
    __syncthreads();
  }
#pragma unroll
  for (int m = 0; m < 4; ++m) {
    const int row0 = bm * 128 + wr + m * 16 + lg * 4;
#pragma unroll
    for (int n = 0; n < 4; ++n) {
      const int col = bn * 128 + wc + n * 16 + l15;
      float bia = 0.f;
      if (bias1) bia += bias1[col];
      if (bias2) bia += bias2[col];
#pragma unroll
      for (int r = 0; r < 4; ++r)
        C[(long)(row0 + r) * N + col] = acc[m][n][r] + bia;
    }
  }
}

// ---------------- fuse: split qkv, +vres mix, LN(q,k), RoPE, -> bf16 QKV ----------------
// qkv fp32 [B,N,3C] with o = which*1024 + h*64 + d. Outputs Q,K,V bf16 [BH, N, 64].
__global__ __launch_bounds__(256)
void fuse_qkv(const float* __restrict__ qkv, const float* __restrict__ vres,
              const float* __restrict__ rope,
              const float* __restrict__ qg, const float* __restrict__ qb,
              const float* __restrict__ kg, const float* __restrict__ kb,
              const float* __restrict__ pl1, const float* __restrict__ pl2,
              u16* __restrict__ Q, u16* __restrict__ K, u16* __restrict__ V) {
  const int t = threadIdx.x, w = t >> 6, d = t & 63;
  const float l1 = pl1[0], l2 = pl2[0];
  const float gq = qg[d], bq = qb[d];
  const float gk = kg[d], bk = kb[d];
  const float sgn = (d < 32) ? -1.f : 1.f;
  const int nw = gridDim.x * 4;
  for (int row = blockIdx.x * 4 + w; row < 65536; row += nw) {
    const int b = row >> 14, h = (row >> 10) & 15, n = row & 1023;
    const long base = ((long)b * 1024 + n) * 3072 + h * 64 + d;
    float q = qkv[base];
    float k = qkv[base + 1024];
    float v = qkv[base + 2048];
    v = l1 * v + l2 * vres[(long)row * 64 + d];
    const float sinv = rope[n * 128 + d];
    const float cosv = rope[n * 128 + 64 + d];
    // LayerNorm over 64 lanes: q
    float s = q;
#pragma unroll
    for (int off = 1; off < 64; off <<= 1) s += __shfl_xor(s, off);
    const float mq = s * (1.f / 64.f);
    const float qc = q - mq;
    float vs = qc * qc;
#pragma unroll
    for (int off = 1; off < 64; off <<= 1) vs += __shfl_xor(vs, off);
    const float qn = qc * (1.f / sqrtf(vs * (1.f / 64.f) + 1e-5f)) * gq + bq;
    // LayerNorm: k
    float s2 = k;
#pragma unroll
    for (int off = 1; off < 64; off <<= 1) s2 += __shfl_xor(s2, off);
    const float mk = s2 * (1.f / 64.f);
    const float kc = k - mk;
    float vs2 = kc * kc;
#pragma unroll
    for (int off = 1; off < 64; off <<= 1) vs2 += __shfl_xor(vs2, off);
    const float kn = kc * (1.f / sqrtf(vs2 * (1.f / 64.f) + 1e-5f)) * gk + bk;
    // RoPE (rotate_half): partner lane d^32; d<32 takes -x[d+32], d>=32 takes +x[d-32]
    const float qo = __shfl_xor(qn, 32);
    const float ko = __shfl_xor(kn, 32);
    const float qr = qn * cosv + sgn * qo * sinv;
    const float kr = kn * cosv + sgn * ko * sinv;
    const long oidx = (long)row * 64 + d;
    Q[oidx] = f2bf(qr);
    K[oidx] = f2bf(kr);
    V[oidx] = f2bf(v);
  }
}

// ---------------- flash attention fwd, bf16, D=64 ----------------
// Q,K,V bf16 [BH=64, N=1024, 64]. Out bf16 [B, N, C] (heads interleaved for proj GEMM).
__global__ __launch_bounds__(256, 2)
void attn_fwd(const u16* __restrict__ Q, const u16* __restrict__ K,
              const u16* __restrict__ V, u16* __restrict__ Out) {
  __shared__ u16 Ks[64][72];
  __shared__ u16 Vt[64][72];
  __shared__ u16 Pl[4][16][72];
  const int t = threadIdx.x, w = t >> 6, l = t & 63;
  const int l15 = l & 15, lg = l >> 4;
  const int bh = blockIdx.x;
  const int q0 = blockIdx.y * 64;
  const u16* Qb = Q + (long)bh * 65536;
  const u16* Kb = K + (long)bh * 65536;
  const u16* Vb = V + (long)bh * 65536;

  // Q fragments held in registers for the whole block
  short8 qf[2];
#pragma unroll
  for (int ks = 0; ks < 2; ++ks)
    qf[ks] = *(const short8*)&Qb[(q0 + w * 16 + l15) * 64 + ks * 32 + lg * 8];

  f32x4 acc_o[4] = {};
  float m_run[4], l_run[4];
#pragma unroll
  for (int r = 0; r < 4; ++r) { m_run[r] = -1e30f; l_run[r] = 0.f; }

  for (int kv = 0; kv < 16; ++kv) {
    const int kvb = kv * 64;
    // stage K (row-major, padded) and V (transposed) into LDS
#pragma unroll
    for (int i = 0; i < 2; ++i) {
      const int idx = i * 256 + t;
      const int row = idx >> 3, seg = idx & 7;
      short8 kd = *(const short8*)&Kb[(kvb + row) * 64 + seg * 8];
      *(short8*)&Ks[row][seg * 8] = kd;
      short8 vd = *(const short8*)&Vb[(kvb + row) * 64 + seg * 8];
#pragma unroll
      for (int j = 0; j < 8; ++j) Vt[seg * 8 + j][row] = (u16)vd[j];
    }
    __syncthreads();
    // scores S = Q K^T (per wave: 16 q-rows x 64 k-cols)
    f32x4 s[4] = {};
#pragma unroll
    for (int kt = 0; kt < 4; ++kt) {
#pragma unroll
      for (int ks = 0; ks < 2; ++ks) {
        short8 bfr = *(const short8*)&Ks[kt * 16 + l15][ks * 32 + lg * 8];
        s[kt] = __builtin_amdgcn_mfma_f32_16x16x32_bf16(qf[ks], bfr, s[kt], 0, 0, 0);
      }
    }
    // online softmax, rows r: q-row = lg*4+r, cols across l15 and kt
    float alpha[4];
#pragma unroll
    for (int r = 0; r < 4; ++r) {
      float mx = fmaxf(fmaxf(s[0][r], s[1][r]), fmaxf(s[2][r], s[3][r])) * 0.125f;
#pragma unroll
      for (int off = 1; off < 16; off <<= 1) mx = fmaxf(mx, __shfl_xor(mx, off));
      const float mn = fmaxf(m_run[r], mx);
      alpha[r] = __expf(m_run[r] - mn);
      m_run[r] = mn;
      float sum = 0.f;
#pragma unroll
      for (int kt = 0; kt < 4; ++kt) {
        const float p = __expf(s[kt][r] * 0.125f - mn);
        s[kt][r] = p;
        sum += p;
      }
#pragma unroll
      for (int off = 1; off < 16; off <<= 1) sum += __shfl_xor(sum, off);
      l_run[r] = l_run[r] * alpha[r] + sum;
    }
    // P -> per-wave LDS (A-fragment layout for PV)
#pragma unroll
    for (int kt = 0; kt < 4; ++kt)
#pragma unroll
      for (int r = 0; r < 4; ++r)
        Pl[w][lg * 4 + r][kt * 16 + l15] = f2bf(s[kt][r]);
    // rescale O accumulators
#pragma unroll
    for (int nt = 0; nt < 4; ++nt)
#pragma unroll
      for (int r = 0; r < 4; ++r) acc_o[nt][r] *= alpha[r];
    // O += P V
#pragma unroll
    for (int nt = 0; nt < 4; ++nt)
#pragma unroll
      for (int ks = 0; ks < 2; ++ks) {
        short8 pa = *(const short8*)&Pl[w][l15][ks * 32 + lg * 8];
        short8 vb = *(const short8*)&Vt[nt * 16 + l15][ks * 32 + lg * 8];
        acc_o[nt] = __builtin_amdgcn_mfma_f32_16x16x32_bf16(pa, vb, acc_o[nt], 0, 0, 0);
      }
    __syncthreads();
  }
  // epilogue: normalize and write [B,N,C]
  const int b = bh >> 4, h = bh & 15;
#pragma unroll
  for (int nt = 0; nt < 4; ++nt)
#pragma unroll
    for (int r = 0; r < 4; ++r) {
      const int qrow = q0 + w * 16 + lg * 4 + r;
      const int col = h * 64 + nt * 16 + l15;
      Out[((long)b * 1024 + qrow) * 1024 + col] = f2bf(acc_o[nt][r] / l_run[r]);
    }
}

extern "C" void kernel_launch(void* const* d_in, const int* in_sizes, int n_in,
                              void* d_out, int out_size, void* d_ws, size_t ws_size,
                              hipStream_t stream) {
  const float* x     = (const float*)d_in[0];
  const float* rope  = (const float*)d_in[1];
  const float* dte   = (const float*)d_in[2];
  const float* vres  = (const float*)d_in[3];
  const float* Wqkv  = (const float*)d_in[4];
  const float* bqkv  = (const float*)d_in[5];
  const float* Wdt   = (const float*)d_in[6];
  const float* bdt   = (const float*)d_in[7];
  const float* qn_g  = (const float*)d_in[8];
  const float* qn_b  = (const float*)d_in[9];
  const float* kn_g  = (const float*)d_in[10];
  const float* kn_b  = (const float*)d_in[11];
  const float* l1    = (const float*)d_in[12];
  const float* l2    = (const float*)d_in[13];
  const float* Wproj = (const float*)d_in[14];
  const float* bproj = (const float*)d_in[15];
  float* out = (float*)d_out;

  char* ws = (char*)d_ws;
  u16*   A_cat = (u16*)(ws);                    // [4096,2048] bf16  (x || dte)
  u16*   W_cat = (u16*)(ws + 16777216);         // [3072,2048] bf16  (Wqkv || Wdt)
  u16*   Wp    = (u16*)(ws + 29360128);         // [1024,1024] bf16
  float* qkv   = (float*)(ws + 31457280);       // [4096,3072] fp32
  u16*   Qb    = (u16*)(ws + 81788928);         // [64,1024,64] bf16
  u16*   Kb    = (u16*)(ws + 90177536);
  u16*   Vb    = (u16*)(ws + 98566144);
  u16*   AO    = (u16*)(ws + 106954752);        // [4096,1024] bf16
  // total ws usage: 115,343,360 bytes

  cvt_cat_bf16<<<2048, 256, 0, stream>>>(x, dte, A_cat, (long)4096 * 2048);
  cvt_cat_bf16<<<2048, 256, 0, stream>>>(Wqkv, Wdt, W_cat, (long)3072 * 2048);
  cvt_bf16<<<1024, 256, 0, stream>>>(Wproj, Wp, (long)1024 * 1024);
  // qkv+dt fused GEMM: [4096,2048] x [3072,2048]^T -> [4096,3072] fp32 (+bqkv+bdt)
  gemm_bt<<<dim3(32, 24), 256, 0, stream>>>(A_cat, W_cat, qkv, bqkv, bdt, 4096, 3072, 2048);
  fuse_qkv<<<2048, 256, 0, stream>>>(qkv, vres, rope, qn_g, qn_b, kn_g, kn_b, l1, l2, Qb, Kb, Vb);
  attn_fwd<<<dim3(64, 16), 256, 0, stream>>>(Qb, Kb, Vb, AO);
  // proj GEMM: [4096,1024] x [1024,1024]^T -> [4096,1024] fp32 (+bproj)
  gemm_bt<<<dim3(32, 8), 256, 0, stream>>>(AO, Wp, out, bproj, nullptr, 4096, 1024, 1024);
}

// Round 2
// 173.185 us; speedup vs baseline: 1.2425x; 1.2425x over previous
//
#include <hip/hip_runtime.h>
#include <stdint.h>

typedef unsigned short u16;
typedef __attribute__((ext_vector_type(8))) short short8;
typedef __attribute__((ext_vector_type(4))) float f32x4;
typedef __attribute__((ext_vector_type(4))) unsigned short u16x4;

#define DEVI __device__ __forceinline__

DEVI u16 f2bf(float f) {
  uint32_t u = __builtin_bit_cast(uint32_t, f);
  u += 0x7fffu + ((u >> 16) & 1u);
  return (u16)(u >> 16);
}

DEVI void gload_lds16(const void* g, void* l) {
  __builtin_amdgcn_global_load_lds(
      (const __attribute__((address_space(1))) void*)g,
      (__attribute__((address_space(3))) void*)(uint32_t)(uintptr_t)l,
      16, 0, 0);
}

// ---------------- convert / concat fp32 -> bf16 ----------------
__global__ void cvt_cat_bf16(const float* __restrict__ a, const float* __restrict__ b,
                             u16* __restrict__ dst, long total) {
  for (long i = ((long)blockIdx.x * 256 + threadIdx.x) * 4; i < total;
       i += (long)gridDim.x * 1024) {
    const long row = i >> 11;
    const long c = i & 2047;
    const float* src = (c < 1024) ? (a + row * 1024 + c) : (b + row * 1024 + (c - 1024));
    const float4 v = *(const float4*)src;
    u16x4 o = {f2bf(v.x), f2bf(v.y), f2bf(v.z), f2bf(v.w)};
    *(u16x4*)(dst + i) = o;
  }
}

__global__ void cvt_bf16(const float* __restrict__ a, u16* __restrict__ dst, long total) {
  for (long i = ((long)blockIdx.x * 256 + threadIdx.x) * 4; i < total;
       i += (long)gridDim.x * 1024) {
    const float4 v = *(const float4*)(a + i);
    u16x4 o = {f2bf(v.x), f2bf(v.y), f2bf(v.z), f2bf(v.w)};
    *(u16x4*)(dst + i) = o;
  }
}

// ---------------- bf16 GEMM, C = A * B^T + bias (m97 structure) ----------------
__global__ __launch_bounds__(256, 2)
void gemm_bt(const u16* __restrict__ A, const u16* __restrict__ B,
             float* __restrict__ C, const float* __restrict__ bias1,
             const float* __restrict__ bias2, int M, int N, int K) {
  __shared__ u16 As[128 * 32];
  __shared__ u16 Bs[128 * 32];
  const int t = threadIdx.x;
  const int w = t >> 6, l = t & 63;
  const int l15 = l & 15, lg = l >> 4;
  const int bm = blockIdx.x, bn = blockIdx.y;
  const int wr = (w >> 1) * 64, wc = (w & 1) * 64;
  f32x4 acc[4][4] = {};
  const int c0 = w * 64 + l;

  for (int kt = 0; kt < (K >> 5); ++kt) {
#pragma unroll
    for (int i = 0; i < 2; ++i) {
      const int c = i * 256 + c0;
      const int row = c >> 2, seg = c & 3;
      gload_lds16(A + (long)(bm * 128 + row) * K + kt * 32 + seg * 8,
                  (char*)As + w * 1024 + i * 4096);
      gload_lds16(B + (long)(bn * 128 + row) * K + kt * 32 + seg * 8,
                  (char*)Bs + w * 1024 + i * 4096);
    }
    __syncthreads();
    short8 af[4], bfr[4];
#pragma unroll
    for (int m = 0; m < 4; ++m)
      af[m] = *(const short8*)&As[(wr + m * 16 + l15) * 32 + lg * 8];
#pragma unroll
    for (int n = 0; n < 4; ++n)
      bfr[n] = *(const short8*)&Bs[(wc + n * 16 + l15) * 32 + lg * 8];
#pragma unroll
    for (int m = 0; m < 4; ++m)
#pragma unroll
      for (int n = 0; n < 4; ++n)
        acc[m][n] = __builtin_amdgcn_mfma_f32_16x16x32_bf16(af[m], bfr[n], acc[m][n], 0, 0, 0);
    __syncthreads();
  }
#pragma unroll
  for (int m = 0; m < 4; ++m) {
    const int row0 = bm * 128 + wr + m * 16 + lg * 4;
#pragma unroll
    for (int n = 0; n < 4; ++n) {
      const int col = bn * 128 + wc + n * 16 + l15;
      float bia = 0.f;
      if (bias1) bia += bias1[col];
      if (bias2) bia += bias2[col];
#pragma unroll
      for (int r = 0; r < 4; ++r)
        C[(long)(row0 + r) * N + col] = acc[m][n][r] + bia;
    }
  }
}

// ---------------- fuse: split qkv, vres mix, LN(q,k), RoPE ----------------
// Outputs: Q row-major [bh][n][64]; Ksw row-major chunk-swizzled (chunk c of row n
// stored at position c^(n&7)); VTsw transposed [bh][d][1024] with per-64-tile
// chunk swizzle (chunk c stored at position c^(d&7)).
__global__ __launch_bounds__(256)
void fuse_qkv2(const float* __restrict__ qkv, const float* __restrict__ vres,
               const float* __restrict__ rope,
               const float* __restrict__ qg, const float* __restrict__ qb,
               const float* __restrict__ kg, const float* __restrict__ kb,
               const float* __restrict__ pl1, const float* __restrict__ pl2,
               u16* __restrict__ Q, u16* __restrict__ Ksw, u16* __restrict__ VTsw) {
  __shared__ u16 Vl[64][72];
  const int t = threadIdx.x, w = t >> 6, d = t & 63;
  const int bh = blockIdx.x, ntile = blockIdx.y;
  const int b = bh >> 4, h = bh & 15, n0 = ntile * 64;
  const float l1 = pl1[0], l2 = pl2[0];
  const float gq = qg[d], bq = qb[d];
  const float gk = kg[d], bk = kb[d];
  const float sgn = (d < 32) ? -1.f : 1.f;
  const int c = d >> 3, d7 = d & 7;

  for (int i = 0; i < 16; ++i) {
    const int nl = w * 16 + i;
    const int n = n0 + nl;
    const long base = ((long)(b * 1024 + n)) * 3072 + h * 64 + d;
    float q = qkv[base];
    float k = qkv[base + 1024];
    float v = qkv[base + 2048];
    v = l1 * v + l2 * vres[((long)(bh * 1024 + n)) * 64 + d];
    const float sinv = rope[n * 128 + d];
    const float cosv = rope[n * 128 + 64 + d];
    // LN q
    float s = q;
#pragma unroll
    for (int off = 1; off < 64; off <<= 1) s += __shfl_xor(s, off);
    const float qc = q - s * (1.f / 64.f);
    float vs = qc * qc;
#pragma unroll
    for (int off = 1; off < 64; off <<= 1) vs += __shfl_xor(vs, off);
    const float qn = qc * (1.f / sqrtf(vs * (1.f / 64.f) + 1e-5f)) * gq + bq;
    // LN k
    float s2 = k;
#pragma unroll
    for (int off = 1; off < 64; off <<= 1) s2 += __shfl_xor(s2, off);
    const float kc = k - s2 * (1.f / 64.f);
    float vs2 = kc * kc;
#pragma unroll
    for (int off = 1; off < 64; off <<= 1) vs2 += __shfl_xor(vs2, off);
    const float kn = kc * (1.f / sqrtf(vs2 * (1.f / 64.f) + 1e-5f)) * gk + bk;
    // RoPE
    const float qo = __shfl_xor(qn, 32);
    const float ko = __shfl_xor(kn, 32);
    const float qr = qn * cosv + sgn * qo * sinv;
    const float kr = kn * cosv + sgn * ko * sinv;
    Q[(long)bh * 65536 + (long)n * 64 + d] = f2bf(qr);
    Ksw[(long)bh * 65536 + (long)n * 64 + ((c ^ (n & 7)) * 8 + d7)] = f2bf(kr);
    Vl[nl][d] = f2bf(v);
  }
  __syncthreads();
  // transpose-write V^T (chunk-swizzled per 64-n tile)
#pragma unroll
  for (int i = 0; i < 2; ++i) {
    const int task = i * 256 + t;
    const int dd = task >> 3, cc = task & 7;
    short8 o;
#pragma unroll
    for (int u = 0; u < 8; ++u) o[u] = (short)Vl[cc * 8 + u][dd];
    *(short8*)&VTsw[((long)(bh * 64 + dd)) * 1024 + n0 + ((cc ^ (dd & 7)) * 8)] = o;
  }
}

// ---------------- flash attention fwd v2: swapped QK^T and PV ----------------
// Q [bh][n][64]; Ksw swizzled row-major; VTsw swizzled [bh][d][n].
// Out bf16 [B,N,C] with heads interleaved.
__global__ __launch_bounds__(256, 4)
void attn_fwd2(const u16* __restrict__ Q, const u16* __restrict__ Ksw,
               const u16* __restrict__ VTsw, u16* __restrict__ Out) {
  __shared__ u16 Kl[64 * 64];
  __shared__ u16 Vl[64 * 64];
  __shared__ u16 Pl[4][16 * 64];
  const int t = threadIdx.x, w = t >> 6, l = t & 63;
  const int l15 = l & 15, lg = l >> 4;
  const int x7 = l15 & 7;
  const int bh = blockIdx.x, q0 = blockIdx.y * 64;
  const long bo = (long)bh * 65536;
  u16* Plw = &Pl[w][0];

  const int qrow = q0 + w * 16 + l15;
  short8 qf[2];
#pragma unroll
  for (int ks = 0; ks < 2; ++ks)
    qf[ks] = *(const short8*)&Q[bo + (long)qrow * 64 + ks * 32 + lg * 8];

  f32x4 acc[4] = {};  // O^T rows d = mt*16+lg*4+r, col q = l15
  float m_run = -1e30f, l_run = 0.f;

  for (int kv = 0; kv < 16; ++kv) {
    const int kvb = kv * 64;
#pragma unroll
    for (int i = 0; i < 2; ++i) {
      const int idx = i * 256 + t;
      const int row = idx >> 3, seg = idx & 7;
      gload_lds16(Ksw + bo + (long)(kvb + row) * 64 + seg * 8, (char*)Kl + idx * 16);
      gload_lds16(VTsw + bo + (long)row * 1024 + kvb + seg * 8, (char*)Vl + idx * 16);
    }
    __syncthreads();
    // S^T = mfma(K, Q): lane holds S^T[k = mt*16+lg*4+r][q = l15]
    f32x4 p[4];
#pragma unroll
    for (int mt = 0; mt < 4; ++mt) {
      f32x4 ps = {};
#pragma unroll
      for (int ks = 0; ks < 2; ++ks) {
        const short8 kf =
            *(const short8*)&Kl[(mt * 16 + l15) * 64 + (((ks * 4 + lg) ^ x7) * 8)];
        ps = __builtin_amdgcn_mfma_f32_16x16x32_bf16(kf, qf[ks], ps, 0, 0, 0);
      }
      p[mt] = ps;
    }
    // online softmax: per-lane over 16 regs + 2 shuffles
    float mx = p[0][0];
#pragma unroll
    for (int mt = 0; mt < 4; ++mt)
#pragma unroll
      for (int r = 0; r < 4; ++r) mx = fmaxf(mx, p[mt][r]);
    mx = fmaxf(mx, __shfl_xor(mx, 16));
    mx = fmaxf(mx, __shfl_xor(mx, 32));
    const float mnew = fmaxf(m_run, mx * 0.125f);
    const float alpha = __expf(m_run - mnew);
    m_run = mnew;
    float sum = 0.f;
#pragma unroll
    for (int mt = 0; mt < 4; ++mt)
#pragma unroll
      for (int r = 0; r < 4; ++r) {
        const float e = __expf(p[mt][r] * 0.125f - mnew);
        p[mt][r] = e;
        sum += e;
      }
    sum += __shfl_xor(sum, 16);
    sum += __shfl_xor(sum, 32);
    l_run = l_run * alpha + sum;
    // store P^T -> per-wave LDS as P[q][k], packed u32, chunk-swizzled
#pragma unroll
    for (int mt = 0; mt < 4; ++mt) {
      const int c = mt * 2 + (lg >> 1);
      char* bp = (char*)Plw + l15 * 128 + ((c ^ x7) * 16) + (lg & 1) * 8;
      *(uint32_t*)bp = (uint32_t)f2bf(p[mt][0]) | ((uint32_t)f2bf(p[mt][1]) << 16);
      *(uint32_t*)(bp + 4) = (uint32_t)f2bf(p[mt][2]) | ((uint32_t)f2bf(p[mt][3]) << 16);
    }
    // rescale O^T (alpha is per-lane uniform for this lane's q-column)
#pragma unroll
    for (int mt = 0; mt < 4; ++mt)
#pragma unroll
      for (int r = 0; r < 4; ++r) acc[mt][r] *= alpha;
    // O^T += mfma(V^T, P): A rows d, B rows q, contraction kv
#pragma unroll
    for (int ks = 0; ks < 2; ++ks) {
      const short8 pf =
          *(const short8*)((char*)Plw + l15 * 128 + (((ks * 4 + lg) ^ x7) * 16));
#pragma unroll
      for (int mt = 0; mt < 4; ++mt) {
        const short8 vf =
            *(const short8*)&Vl[(mt * 16 + l15) * 64 + (((ks * 4 + lg) ^ x7) * 8)];
        acc[mt] = __builtin_amdgcn_mfma_f32_16x16x32_bf16(vf, pf, acc[mt], 0, 0, 0);
      }
    }
    __syncthreads();
  }
  // epilogue: O[q][d] = O^T[d][q] / l; write [B,N,C]
  const int b = bh >> 4, h = bh & 15;
  const float inv = 1.f / l_run;
  const long obase = ((long)(b * 1024 + qrow)) * 1024 + h * 64;
#pragma unroll
  for (int mt = 0; mt < 4; ++mt) {
    const long o = obase + mt * 16 + lg * 4;
    *(uint32_t*)&Out[o] =
        (uint32_t)f2bf(acc[mt][0] * inv) | ((uint32_t)f2bf(acc[mt][1] * inv) << 16);
    *(uint32_t*)&Out[o + 2] =
        (uint32_t)f2bf(acc[mt][2] * inv) | ((uint32_t)f2bf(acc[mt][3] * inv) << 16);
  }
}

extern "C" void kernel_launch(void* const* d_in, const int* in_sizes, int n_in,
                              void* d_out, int out_size, void* d_ws, size_t ws_size,
                              hipStream_t stream) {
  const float* x     = (const float*)d_in[0];
  const float* rope  = (const float*)d_in[1];
  const float* dte   = (const float*)d_in[2];
  const float* vres  = (const float*)d_in[3];
  const float* Wqkv  = (const float*)d_in[4];
  const float* bqkv  = (const float*)d_in[5];
  const float* Wdt   = (const float*)d_in[6];
  const float* bdt   = (const float*)d_in[7];
  const float* qn_g  = (const float*)d_in[8];
  const float* qn_b  = (const float*)d_in[9];
  const float* kn_g  = (const float*)d_in[10];
  const float* kn_b  = (const float*)d_in[11];
  const float* l1    = (const float*)d_in[12];
  const float* l2    = (const float*)d_in[13];
  const float* Wproj = (const float*)d_in[14];
  const float* bproj = (const float*)d_in[15];
  float* out = (float*)d_out;

  char* ws = (char*)d_ws;
  u16*   A_cat = (u16*)(ws);                    // [4096,2048] bf16
  u16*   W_cat = (u16*)(ws + 16777216);         // [3072,2048] bf16
  u16*   Wp    = (u16*)(ws + 29360128);         // [1024,1024] bf16
  float* qkv   = (float*)(ws + 31457280);       // [4096,3072] fp32
  u16*   Qb    = (u16*)(ws + 81788928);         // [64,1024,64] bf16
  u16*   Ksw   = (u16*)(ws + 90177536);         // swizzled K
  u16*   VTsw  = (u16*)(ws + 98566144);         // swizzled V^T
  u16*   AO    = (u16*)(ws + 106954752);        // [4096,1024] bf16

  cvt_cat_bf16<<<2048, 256, 0, stream>>>(x, dte, A_cat, (long)4096 * 2048);
  cvt_cat_bf16<<<2048, 256, 0, stream>>>(Wqkv, Wdt, W_cat, (long)3072 * 2048);
  cvt_bf16<<<1024, 256, 0, stream>>>(Wproj, Wp, (long)1024 * 1024);
  gemm_bt<<<dim3(32, 24), 256, 0, stream>>>(A_cat, W_cat, qkv, bqkv, bdt, 4096, 3072, 2048);
  fuse_qkv2<<<dim3(64, 16), 256, 0, stream>>>(qkv, vres, rope, qn_g, qn_b, kn_g, kn_b,
                                              l1, l2, Qb, Ksw, VTsw);
  attn_fwd2<<<dim3(64, 16), 256, 0, stream>>>(Qb, Ksw, VTsw, AO);
  gemm_bt<<<dim3(32, 8), 256, 0, stream>>>(AO, Wp, out, bproj, nullptr, 4096, 1024, 1024);
}